// Round 2
// baseline (618.610 us; speedup 1.0000x reference)
//
#include <hip/hip_runtime.h>

// UnfoldTransposeNd: x (16,64,64,64) f32 -> out (16, 576, 128*128) f32
// out[b, c*9 + jh*3 + jw, oh, ow] = x[b, c, ih, iw]
//   where rh = oh+1-jh, rw = ow+1-jw must be >=0, even, and rh/2, rw/2 < 64.
// Memory-bound: 604 MB coalesced float4 stores; input (16.7 MB) is L2/L3 hot.

#define C_ 64
#define HW_ 64
#define OW_ 128
#define OH_ 128
#define KK_ 9

__global__ __launch_bounds__(256) void unfold_t2d_kernel(
    const float* __restrict__ x, float* __restrict__ out, int n4) {
    int i4 = blockIdx.x * 256 + threadIdx.x;
    if (i4 >= n4) return;

    // 32 float4 per output row of 128 floats
    int ow0 = (i4 & 31) << 2;
    int row = i4 >> 5;            // ((b*C + c)*9 + j)*128 + oh
    int oh  = row & 127;
    int t   = row >> 7;           // (b*C + c)*9 + j
    int j   = t % 9;
    int cc  = t / 9;              // b*C + c  (flat channel index into x)
    int jh  = j / 3;
    int jw  = j - jh * 3;

    int rh = oh + 1 - jh;
    int ih = rh >> 1;
    bool vh = (rh >= 0) & ((rh & 1) == 0) & (ih < HW_);

    float4 o = make_float4(0.f, 0.f, 0.f, 0.f);
    if (vh) {
        const float* xrow = x + (cc * HW_ + ih) * HW_;
        float* po = &o.x;
#pragma unroll
        for (int q = 0; q < 4; ++q) {
            int rw = ow0 + q + 1 - jw;
            int iw = rw >> 1;
            if (rw >= 0 && (rw & 1) == 0 && iw < HW_) {
                po[q] = xrow[iw];
            }
        }
    }
    reinterpret_cast<float4*>(out)[i4] = o;
}

extern "C" void kernel_launch(void* const* d_in, const int* in_sizes, int n_in,
                              void* d_out, int out_size, void* d_ws, size_t ws_size,
                              hipStream_t stream) {
    const float* x = (const float*)d_in[0];
    float* out = (float*)d_out;
    int n4 = out_size >> 2;                 // 150,994,944 / 4 = 37,748,736
    int blocks = (n4 + 255) / 256;          // 147,456
    unfold_t2d_kernel<<<blocks, 256, 0, stream>>>(x, out, n4);
}